// Round 2
// baseline (170.545 us; speedup 1.0000x reference)
//
#include <hip/hip_runtime.h>
#include <hip/hip_bf16.h>

#define GG   48
#define DD   256
#define HH   30
#define PP   1128      // GG*(GG-1)/2
#define VPAD 260       // pad rows of v to break 1KB-stride LDS bank conflicts

#define OFF(i) (((i) * (95 - (i))) >> 1)   // pairs before row i (G=48)

__device__ __forceinline__ float sg(float x) { return 1.0f / (1.0f + __expf(-x)); }

// Process T consecutive pairs starting at pair index p0.
// Computes z[0..30] = e . W1aug (col 30 is the p-vector column), then the
// attention logit a_p = sigmoid(W2 . sigmoid(z+b1) + b2) and s_p = z[30].
template <int T>
__device__ __forceinline__ void pair_chunk(
    int p0,
    const float (*v)[VPAD], const float (*w1)[32],
    const float* b1_s, const float* w2_s, float b2v,
    float* a_s, float* s_s)
{
    // pair index -> (i, j), triu_indices(48, k=1) order
    int i = (int)((95.0f - sqrtf(9025.0f - 8.0f * (float)p0)) * 0.5f);
    i = max(0, min(46, i));
    while (i < 46 && OFF(i + 1) <= p0) ++i;
    while (i > 0 && OFF(i) > p0) --i;
    int j = i + 1 + (p0 - OFF(i));

    int ii[T], jj[T];
#pragma unroll
    for (int t = 0; t < T; ++t) {
        ii[t] = i; jj[t] = j;
        if (++j == GG) { ++i; j = i + 1; }
    }

    float acc[T][32];
#pragma unroll
    for (int t = 0; t < T; ++t)
#pragma unroll
        for (int h = 0; h < 32; ++h) acc[t][h] = 0.0f;

    for (int d = 0; d < DD; d += 4) {
        float4 vi[T], vj[T];
#pragma unroll
        for (int t = 0; t < T; ++t) {
            vi[t] = *(const float4*)&v[ii[t]][d];
            vj[t] = *(const float4*)&v[jj[t]][d];
        }
#pragma unroll
        for (int dd = 0; dd < 4; ++dd) {
            float e[T];
#pragma unroll
            for (int t = 0; t < T; ++t)
                e[t] = ((const float*)&vi[t])[dd] * ((const float*)&vj[t])[dd];
#pragma unroll
            for (int hq = 0; hq < 8; ++hq) {
                float4 w = *(const float4*)&w1[d + dd][hq * 4];
#pragma unroll
                for (int t = 0; t < T; ++t) {
                    acc[t][hq * 4 + 0] = fmaf(e[t], w.x, acc[t][hq * 4 + 0]);
                    acc[t][hq * 4 + 1] = fmaf(e[t], w.y, acc[t][hq * 4 + 1]);
                    acc[t][hq * 4 + 2] = fmaf(e[t], w.z, acc[t][hq * 4 + 2]);
                    acc[t][hq * 4 + 3] = fmaf(e[t], w.w, acc[t][hq * 4 + 3]);
                }
            }
        }
    }

#pragma unroll
    for (int t = 0; t < T; ++t) {
        float aa = b2v;
#pragma unroll
        for (int h = 0; h < HH; ++h)
            aa = fmaf(sg(acc[t][h] + b1_s[h]), w2_s[h], aa);
        a_s[p0 + t] = sg(aa);
        s_s[p0 + t] = acc[t][30];
    }
}

__global__ __launch_bounds__(256, 1)
void afm_kernel(const int* __restrict__ group, const float* __restrict__ pe,
                const float* __restrict__ fe, const float* __restrict__ p,
                const float* __restrict__ W1, const float* __restrict__ b1,
                const float* __restrict__ W2, const float* __restrict__ b2,
                float* __restrict__ out)
{
    __shared__ float v[GG][VPAD];        // 49920 B
    __shared__ float w1aug[DD][32];      // 32768 B  (col 30 = p, col 31 = 0)
    __shared__ float a_s[PP];            // 4512 B
    __shared__ float s_s[PP];            // 4512 B
    __shared__ int   gidx[GG];
    __shared__ float b1_s[HH];
    __shared__ float w2_s[HH];
    __shared__ float red[16];

    const int tid = threadIdx.x;
    const int b   = blockIdx.x;

    if (tid < GG) gidx[tid] = group[b * GG + tid];
    if (tid >= 64 && tid < 64 + HH) {
        int h = tid - 64;
        b1_s[h] = b1[h];
        w2_s[h] = W2[h];
    }
    __syncthreads();

    // first-order term contribution (one scalar per group slot)
    float ff = 0.0f;
    if (tid < GG) ff = fe[gidx[tid]];

    // gather v rows (coalesced float4, 4 rows per sweep)
    {
        int r = tid >> 6;          // 0..3
        int c = (tid & 63) * 4;    // 0..252
        for (int g0 = 0; g0 < GG; g0 += 4) {
            int g = g0 + r;
            const float* src = pe + (size_t)gidx[g] * DD + c;
            *(float4*)&v[g][c] = *(const float4*)src;
        }
    }
    // stage W1 augmented with the p column
    for (int k = tid; k < DD * HH; k += 256) {
        int d = k / HH, h = k - d * HH;
        w1aug[d][h] = W1[k];
    }
    for (int d = tid; d < DD; d += 256) {
        w1aug[d][30] = p[d];
        w1aug[d][31] = 0.0f;
    }
    __syncthreads();

    const float b2v = b2[0];

    // phase 1: pairs 0..1023, 4 consecutive pairs per thread
    pair_chunk<4>(tid * 4, v, w1aug, b1_s, w2_s, b2v, a_s, s_s);

    // phase 2: pairs 1024..1127, 1 pair per thread (tid < 104)
    if (tid < PP - 1024)
        pair_chunk<1>(1024 + tid, v, w1aug, b1_s, w2_s, b2v, a_s, s_s);

    __syncthreads();

    // softmax over 1128 pairs + weighted sum + first-order
    float lm = -1e30f;
    for (int q = tid; q < PP; q += 256) lm = fmaxf(lm, a_s[q]);
#pragma unroll
    for (int o = 32; o > 0; o >>= 1) lm = fmaxf(lm, __shfl_down(lm, o));
    if ((tid & 63) == 0) red[tid >> 6] = lm;
    __syncthreads();
    const float m = fmaxf(fmaxf(red[0], red[1]), fmaxf(red[2], red[3]));

    float ls = 0.0f, ln = 0.0f;
    for (int q = tid; q < PP; q += 256) {
        float ea = __expf(a_s[q] - m);
        ls += ea;
        ln += ea * s_s[q];
    }
    float lf = ff;
#pragma unroll
    for (int o = 32; o > 0; o >>= 1) {
        ls += __shfl_down(ls, o);
        ln += __shfl_down(ln, o);
        lf += __shfl_down(lf, o);
    }
    if ((tid & 63) == 0) {
        int w = tid >> 6;
        red[4 + w]  = ls;
        red[8 + w]  = ln;
        red[12 + w] = lf;
    }
    __syncthreads();
    if (tid == 0) {
        float denom  = red[4] + red[5] + red[6] + red[7];
        float num    = red[8] + red[9] + red[10] + red[11];
        float first  = red[12] + red[13] + red[14] + red[15];
        float second = num / denom;
        out[b] = sg(first + second) * 2.0f - 1.0f;
    }
}

extern "C" void kernel_launch(void* const* d_in, const int* in_sizes, int n_in,
                              void* d_out, int out_size, void* d_ws, size_t ws_size,
                              hipStream_t stream)
{
    const int*   group = (const int*)d_in[0];
    const float* pe    = (const float*)d_in[1];
    const float* fe    = (const float*)d_in[2];
    const float* p     = (const float*)d_in[3];
    const float* W1    = (const float*)d_in[4];
    const float* b1    = (const float*)d_in[5];
    const float* W2    = (const float*)d_in[6];
    const float* b2    = (const float*)d_in[7];
    float* out = (float*)d_out;

    afm_kernel<<<512, 256, 0, stream>>>(group, pe, fe, p, W1, b1, W2, b2, out);
}

// Round 3
// 60.413 us; speedup vs baseline: 2.8230x; 2.8230x over previous
//
#include <hip/hip_runtime.h>
#include <hip/hip_bf16.h>

#define GG   48
#define DD   256
#define HH   30
#define PP   1128           // GG*(GG-1)/2
#define VROW 264            // bf16 elems per padded LDS row (528 B: +4 banks/row)
#define NT   72             // M-tiles of 16 pairs (72*16 = 1152 >= 1128)

#define OFF(i) (((i) * (95 - (i))) >> 1)   // pairs before row i (G=48)

typedef __attribute__((ext_vector_type(8))) short short8;
typedef __attribute__((ext_vector_type(4))) float f32x4;

union U16x8 { uint4 u; short8 s; };

__device__ __forceinline__ float sg(float x) { return 1.0f / (1.0f + __expf(-x)); }

__global__ __launch_bounds__(256)
void afm_kernel(const int* __restrict__ group, const float* __restrict__ pe,
                const float* __restrict__ fe, const float* __restrict__ p,
                const float* __restrict__ W1, const float* __restrict__ b1,
                const float* __restrict__ W2, const float* __restrict__ b2,
                float* __restrict__ out)
{
    __shared__ __hip_bfloat16 v[GG][VROW];     // 25344 B
    __shared__ __hip_bfloat16 w1t[32][VROW];   // 16896 B (rows: 30 W1 cols, p, 0)
    __shared__ unsigned       tab[PP];         // 4512 B  (i,j byte offsets packed)
    __shared__ float          a_s[PP];         // 4512 B
    __shared__ float          s_s[PP];         // 4512 B
    __shared__ int            gidx[GG];
    __shared__ float          red[16];

    const int tid  = threadIdx.x;
    const int b    = blockIdx.x;
    const int lane = tid & 63;
    const int wv   = tid >> 6;       // wave 0..3
    const int colB = lane & 15;      // MFMA col / A row
    const int kgrp = lane >> 4;      // k-group 0..3

    if (tid < GG) gidx[tid] = group[b * GG + tid];
    __syncthreads();

    float ff = 0.0f;
    if (tid < GG) ff = fe[gidx[tid]];

    // per-thread MLP constants (h = colB and 16+colB; cols 30,31 are p/zero)
    const float b1r0 = b1[colB];
    const float b1r1 = (colB < HH - 16) ? b1[16 + colB] : 0.0f;
    const float w2r0 = W2[colB];
    const float w2r1 = (colB < HH - 16) ? W2[16 + colB] : 0.0f;
    const float b2v  = b2[0];

    // stage v rows as bf16 (coalesced float4 gather, 4 rows per sweep)
    {
        int r = tid >> 6, c = (tid & 63) * 4;
        for (int g0 = 0; g0 < GG; g0 += 4) {
            int g = g0 + r;
            float4 f = *(const float4*)(pe + (size_t)gidx[g] * DD + c);
            __hip_bfloat162 lo = __float22bfloat162_rn(make_float2(f.x, f.y));
            __hip_bfloat162 hi = __float22bfloat162_rn(make_float2(f.z, f.w));
            *(__hip_bfloat162*)&v[g][c]     = lo;
            *(__hip_bfloat162*)&v[g][c + 2] = hi;
        }
    }
    // stage W1^T (bf16), augmented: row 30 = p, row 31 = 0
    {
        int d = tid;  // 256 threads == DD
        for (int h = 0; h < HH; ++h)
            w1t[h][d] = __float2bfloat16(W1[d * HH + h]);
        w1t[30][d] = __float2bfloat16(p[d]);
        w1t[31][d] = __float2bfloat16(0.0f);
    }
    // pair -> (i,j) byte-offset table
    for (int pr = tid; pr < PP; pr += 256) {
        int i = (int)((95.0f - sqrtf(9025.0f - 8.0f * (float)pr)) * 0.5f);
        i = max(0, min(46, i));
        while (i < 46 && OFF(i + 1) <= pr) ++i;
        while (i > 0 && OFF(i) > pr) --i;
        int j = i + 1 + (pr - OFF(i));
        tab[pr] = (unsigned)(i * (VROW * 2)) | ((unsigned)(j * (VROW * 2)) << 16);
    }
    __syncthreads();

    // all 16 B fragments in registers: B[k][n], n = nt*16+colB, k = kt*32+kgrp*8+e
    short8 Bf0[8], Bf1[8];
#pragma unroll
    for (int kt = 0; kt < 8; ++kt) {
        Bf0[kt] = *(const short8*)&w1t[colB][kt * 32 + kgrp * 8];
        Bf1[kt] = *(const short8*)&w1t[16 + colB][kt * 32 + kgrp * 8];
    }

    const char* vbase = (const char*)&v[0][0];
    const unsigned kbyte = (unsigned)(kgrp * 16);

    for (int t = 0; t < 18; ++t) {
        const int tile = wv + 4 * t;             // 0..71
        const int prA  = tile * 16 + colB;       // this lane's A row (pair)
        const unsigned ab = tab[prA < PP ? prA : PP - 1];
        const char* pi = vbase + (ab & 0xffffu) + kbyte;
        const char* pj = vbase + (ab >> 16) + kbyte;

        f32x4 acc0 = {0.f, 0.f, 0.f, 0.f};
        f32x4 acc1 = {0.f, 0.f, 0.f, 0.f};
#pragma unroll
        for (int kt = 0; kt < 8; ++kt) {
            uint4 ui = *(const uint4*)(pi + kt * 64);
            uint4 uj = *(const uint4*)(pj + kt * 64);
            unsigned xs[4] = {ui.x, ui.y, ui.z, ui.w};
            unsigned ys[4] = {uj.x, uj.y, uj.z, uj.w};
            unsigned ao[4];
#pragma unroll
            for (int q = 0; q < 4; ++q) {
                float il = __uint_as_float(xs[q] << 16);
                float ih = __uint_as_float(xs[q] & 0xffff0000u);
                float jl = __uint_as_float(ys[q] << 16);
                float jh = __uint_as_float(ys[q] & 0xffff0000u);
                __hip_bfloat162 pk = __float22bfloat162_rn(make_float2(il * jl, ih * jh));
                ao[q] = *(unsigned*)&pk;
            }
            U16x8 A;
            A.u = make_uint4(ao[0], ao[1], ao[2], ao[3]);
            acc0 = __builtin_amdgcn_mfma_f32_16x16x32_bf16(A.s, Bf0[kt], acc0, 0, 0, 0);
            acc1 = __builtin_amdgcn_mfma_f32_16x16x32_bf16(A.s, Bf1[kt], acc1, 0, 0, 0);
        }

        // epilogue: per pair row, a = sg(sum_h sg(z_h+b1_h)*w2_h + b2), s = z[:,30]
#pragma unroll
        for (int r = 0; r < 4; ++r) {
            float tsum = sg(acc0[r] + b1r0) * w2r0 + sg(acc1[r] + b1r1) * w2r1;
            tsum += __shfl_xor(tsum, 1, 16);
            tsum += __shfl_xor(tsum, 2, 16);
            tsum += __shfl_xor(tsum, 4, 16);
            tsum += __shfl_xor(tsum, 8, 16);
            int prw = tile * 16 + kgrp * 4 + r;  // C row = (lane>>4)*4 + reg
            if (prw < PP) {
                if (colB == 0)  a_s[prw] = sg(tsum + b2v);
                if (colB == 14) s_s[prw] = acc1[r];   // col 30 = 16+14
            }
        }
    }
    __syncthreads();

    // softmax over 1128 pairs + weighted sum + first-order
    float lm = -1e30f;
    for (int q = tid; q < PP; q += 256) lm = fmaxf(lm, a_s[q]);
#pragma unroll
    for (int o = 32; o > 0; o >>= 1) lm = fmaxf(lm, __shfl_down(lm, o));
    if ((tid & 63) == 0) red[tid >> 6] = lm;
    __syncthreads();
    const float m = fmaxf(fmaxf(red[0], red[1]), fmaxf(red[2], red[3]));

    float ls = 0.0f, ln = 0.0f;
    for (int q = tid; q < PP; q += 256) {
        float ea = __expf(a_s[q] - m);
        ls += ea;
        ln += ea * s_s[q];
    }
    float lf = ff;
#pragma unroll
    for (int o = 32; o > 0; o >>= 1) {
        ls += __shfl_down(ls, o);
        ln += __shfl_down(ln, o);
        lf += __shfl_down(lf, o);
    }
    if ((tid & 63) == 0) {
        int w = tid >> 6;
        red[4 + w]  = ls;
        red[8 + w]  = ln;
        red[12 + w] = lf;
    }
    __syncthreads();
    if (tid == 0) {
        float denom  = red[4] + red[5] + red[6] + red[7];
        float num    = red[8] + red[9] + red[10] + red[11];
        float first  = red[12] + red[13] + red[14] + red[15];
        float second = num / denom;
        out[b] = sg(first + second) * 2.0f - 1.0f;
    }
}

extern "C" void kernel_launch(void* const* d_in, const int* in_sizes, int n_in,
                              void* d_out, int out_size, void* d_ws, size_t ws_size,
                              hipStream_t stream)
{
    const int*   group = (const int*)d_in[0];
    const float* pe    = (const float*)d_in[1];
    const float* fe    = (const float*)d_in[2];
    const float* p     = (const float*)d_in[3];
    const float* W1    = (const float*)d_in[4];
    const float* b1    = (const float*)d_in[5];
    const float* W2    = (const float*)d_in[6];
    const float* b2    = (const float*)d_in[7];
    float* out = (float*)d_out;

    afm_kernel<<<512, 256, 0, stream>>>(group, pe, fe, p, W1, b1, W2, b2, out);
}

// Round 4
// 34.945 us; speedup vs baseline: 4.8804x; 1.7288x over previous
//
#include <hip/hip_runtime.h>

#define GG   48
#define DD   256
#define HH   30
#define PP   1128          // GG*(GG-1)/2
#define VROW 264           // fp16 elems per padded LDS row (528 B, 16B-aligned)

#define OFF(i) (((i) * (95 - (i))) >> 1)   // pairs before row i (G=48)

typedef _Float16 half8 __attribute__((ext_vector_type(8)));
typedef _Float16 half4 __attribute__((ext_vector_type(4)));
typedef float    f32x4 __attribute__((ext_vector_type(4)));

__device__ __forceinline__ float sg(float x) { return 1.0f / (1.0f + __expf(-x)); }

__global__ __launch_bounds__(256, 2)
void afm_kernel(const int* __restrict__ group, const float* __restrict__ pe,
                const float* __restrict__ fe, const float* __restrict__ p,
                const float* __restrict__ W1, const float* __restrict__ b1,
                const float* __restrict__ W2, const float* __restrict__ b2,
                float* __restrict__ out)
{
    __shared__ __align__(16) _Float16 v[GG][VROW];      // 25344 B
    __shared__ __align__(16) union SU {
        _Float16 w1t[32][VROW];                          // 16896 B (rows: 30 W1 cols, p, 0)
        struct { float a_s[PP]; float s_s[PP]; } r;      // 9024 B, live after w1t dies
    } u;
    __shared__ int   gidx[GG];
    __shared__ float red[16];

    const int tid  = threadIdx.x;
    const int b    = blockIdx.x;
    const int lane = tid & 63;
    const int wv   = tid >> 6;       // wave 0..3
    const int colB = lane & 15;      // fragment row/col index
    const int kgrp = lane >> 4;      // k-group 0..3

    if (tid < GG) gidx[tid] = group[b * GG + tid];
    __syncthreads();

    float ff = (tid < GG) ? fe[gidx[tid]] : 0.0f;

    // per-lane MLP constants: this lane's C rows are h = kgrp*4+r (acc0) and
    // 16+kgrp*4+r (acc1). h=30 is the p-column, h=31 the zero column -> w2=0.
    float b1h[8], w2h[8];
#pragma unroll
    for (int r = 0; r < 4; ++r) {
        int h0 = kgrp * 4 + r;
        int h1 = 16 + kgrp * 4 + r;
        b1h[r]     = b1[h0];
        w2h[r]     = W2[h0];
        b1h[4 + r] = (h1 < HH) ? b1[h1] : 0.0f;
        w2h[4 + r] = (h1 < HH) ? W2[h1] : 0.0f;
    }
    const float b2v = b2[0];

    // stage v rows as fp16 (coalesced float4 gather, 4 rows per sweep)
    {
        int rr = tid >> 6, c = (tid & 63) * 4;
        for (int g0 = 0; g0 < GG; g0 += 4) {
            int g = g0 + rr;
            float4 f = *(const float4*)(pe + (size_t)gidx[g] * DD + c);
            half4 h4 = { (_Float16)f.x, (_Float16)f.y, (_Float16)f.z, (_Float16)f.w };
            *(half4*)&v[g][c] = h4;
        }
    }
    // stage W1^T (fp16), augmented: row 30 = p, row 31 = 0. Flat coalesced read.
    for (int k = tid; k < DD * HH; k += 256) {
        int d = k / HH, h = k - d * HH;
        u.w1t[h][d] = (_Float16)W1[k];
    }
    u.w1t[30][tid] = (_Float16)p[tid];
    u.w1t[31][tid] = (_Float16)0.0f;
    __syncthreads();

    // W fragments (A operand): lane holds rows h=colB and h=16+colB, k-chunk kgrp*8
    half8 wf0[8], wf1[8];
    {
        const _Float16* w0p = &u.w1t[colB][kgrp * 8];
        const _Float16* w1p = &u.w1t[16 + colB][kgrp * 8];
#pragma unroll
        for (int kt = 0; kt < 8; ++kt) {
            wf0[kt] = *(const half8*)(w0p + kt * 32);
            wf1[kt] = *(const half8*)(w1p + kt * 32);
        }
    }
    __syncthreads();   // all waves done reading w1t; a_s/s_s may now overwrite it

    // main loop: tiles (I-block of 16 i's) x (single j), j > I0, wave-strided by 4
    for (int ib = 0; ib < 3; ++ib) {
        const int I0   = ib * 16;
        const int i_me = I0 + colB;          // this lane's pair-i (B-operand col)
        half8 vif[8];
        {
            const _Float16* vr = &v[i_me][kgrp * 8];
#pragma unroll
            for (int kt = 0; kt < 8; ++kt) vif[kt] = *(const half8*)(vr + kt * 32);
        }

        for (int j = I0 + 1 + wv; j < GG; j += 4) {
            const _Float16* vjp = &v[j][kgrp * 8];   // broadcast-class reads
            f32x4 acc0 = {0.f, 0.f, 0.f, 0.f};
            f32x4 acc1 = {0.f, 0.f, 0.f, 0.f};
#pragma unroll
            for (int kt = 0; kt < 8; ++kt) {
                half8 e = vif[kt] * (*(const half8*)(vjp + kt * 32));  // 4 v_pk_mul_f16
                acc0 = __builtin_amdgcn_mfma_f32_16x16x32_f16(wf0[kt], e, acc0, 0, 0, 0);
                acc1 = __builtin_amdgcn_mfma_f32_16x16x32_f16(wf1[kt], e, acc1, 0, 0, 0);
            }
            // C: row = h (kgrp*4+r / +16), col = pair q = colB. In-lane MLP partial:
            float t = 0.0f;
#pragma unroll
            for (int r = 0; r < 4; ++r) {
                t += sg(acc0[r] + b1h[r]) * w2h[r];
                t += sg(acc1[r] + b1h[4 + r]) * w2h[4 + r];   // masked terms add 0
            }
            t += __shfl_xor(t, 16);
            t += __shfl_xor(t, 32);
            if (i_me < j) {
                int pidx = OFF(i_me) + (j - i_me - 1);
                if (kgrp == 0) u.r.a_s[pidx] = sg(t + b2v);
                if (kgrp == 3) u.r.s_s[pidx] = acc1[2];   // h = 16+3*4+2 = 30 (e.p)
            }
        }
    }
    __syncthreads();

    // softmax over 1128 pairs + weighted sum + first-order
    float lm = -1e30f;
    for (int q = tid; q < PP; q += 256) lm = fmaxf(lm, u.r.a_s[q]);
#pragma unroll
    for (int o = 32; o > 0; o >>= 1) lm = fmaxf(lm, __shfl_down(lm, o));
    if ((tid & 63) == 0) red[tid >> 6] = lm;
    __syncthreads();
    const float m = fmaxf(fmaxf(red[0], red[1]), fmaxf(red[2], red[3]));

    float ls = 0.0f, ln = 0.0f;
    for (int q = tid; q < PP; q += 256) {
        float ea = __expf(u.r.a_s[q] - m);
        ls += ea;
        ln += ea * u.r.s_s[q];
    }
    float lf = ff;
#pragma unroll
    for (int o = 32; o > 0; o >>= 1) {
        ls += __shfl_down(ls, o);
        ln += __shfl_down(ln, o);
        lf += __shfl_down(lf, o);
    }
    if ((tid & 63) == 0) {
        int w = tid >> 6;
        red[4 + w]  = ls;
        red[8 + w]  = ln;
        red[12 + w] = lf;
    }
    __syncthreads();
    if (tid == 0) {
        float denom  = red[4] + red[5] + red[6] + red[7];
        float num    = red[8] + red[9] + red[10] + red[11];
        float first  = red[12] + red[13] + red[14] + red[15];
        float second = num / denom;
        out[b] = sg(first + second) * 2.0f - 1.0f;
    }
}

extern "C" void kernel_launch(void* const* d_in, const int* in_sizes, int n_in,
                              void* d_out, int out_size, void* d_ws, size_t ws_size,
                              hipStream_t stream)
{
    const int*   group = (const int*)d_in[0];
    const float* pe    = (const float*)d_in[1];
    const float* fe    = (const float*)d_in[2];
    const float* p     = (const float*)d_in[3];
    const float* W1    = (const float*)d_in[4];
    const float* b1    = (const float*)d_in[5];
    const float* W2    = (const float*)d_in[6];
    const float* b2    = (const float*)d_in[7];
    float* out = (float*)d_out;

    afm_kernel<<<512, 256, 0, stream>>>(group, pe, fe, p, W1, b1, W2, b2, out);
}